// Round 1
// baseline (1218.413 us; speedup 1.0000x reference)
//
#include <hip/hip_runtime.h>
#include <math.h>

using bf16 = __bf16;
using bf16x8 = __attribute__((ext_vector_type(8))) __bf16;
using f32x4 = __attribute__((ext_vector_type(4))) float;

static __device__ __forceinline__ int imin(int a, int b) { return a < b ? a : b; }
// XOR swizzle: 16B-chunk rotate within a row, bits 4-6, keyed by row&7.
// Rows >= 128B wide get full 3-bit spread -> <=2-way bank conflicts.
static __device__ __forceinline__ uint32_t swz(int row, uint32_t colb) {
  return colb ^ (uint32_t)((row & 7) << 4);
}
static __device__ __forceinline__ float gelu_f(float v) {
  return 0.5f * v * (1.0f + erff(v * 0.7071067811865475f));
}

// ---- weight conversion: fp32 -> bf16 into workspace ----
// wqkv = [qk_w (512x256) ; v_w (1024x256)]  (row-major [o][c])
// wproj = proj_w (256x1024) row-major [o][c]
__global__ void conv_w_kernel(const float* __restrict__ qk_w,
                              const float* __restrict__ v_w,
                              const float* __restrict__ proj_w,
                              bf16* __restrict__ wqkv,
                              bf16* __restrict__ wproj) {
  int i = blockIdx.x * 256 + threadIdx.x;
  if (i < 131072)       wqkv[i] = (bf16)qk_w[i];
  else if (i < 393216)  wqkv[i] = (bf16)v_w[i - 131072];
  else if (i < 655360)  wproj[i - 393216] = (bf16)proj_w[i - 393216];
}

// LDS layout (bytes), total 155648:
//   A   @ 0      : ln(x) bf16 [64][256], row stride 512B, swizzled (rows 49..63 zero)
//   ATT @ 32768  : attn bf16 [8 heads][56][64], row stride 128B, swizzled
//   R2  @ 90112  : phase1-2: QK bf16 [8][56][64] (cols 0-31=Q_d, 32-63=K_d), stride 128B
//                  phase3+:  V  bf16 [8][64 vd][64 m], stride 128B (transposed for PV B-op)
//   XM  @ 32768  : [56][1024] bf16, stride 2048B, swizzled (overlays ATT+R2 after PV)
__global__ void __launch_bounds__(512, 2)
irmb_main(const float* __restrict__ x,
          const float* __restrict__ pre_g,  const float* __restrict__ pre_b,
          const float* __restrict__ post_g, const float* __restrict__ post_b,
          const float* __restrict__ qk_bias, const float* __restrict__ v_bias,
          const float* __restrict__ proj_bias, const float* __restrict__ rpb,
          const bf16* __restrict__ wqkv, const bf16* __restrict__ wproj,
          float* __restrict__ out)
{
  extern __shared__ char smem[];
  char* Abase = smem;
  char* ATT   = smem + 32768;
  char* R2    = smem + 90112;
  char* XMb   = smem + 32768;

  const int tid  = threadIdx.x;
  const int lane = tid & 63;
  const int wv   = tid >> 6;      // wave id 0..7
  const int l15  = lane & 15;
  const int g4   = lane >> 4;     // 0..3
  const int bb   = blockIdx.x >> 6;   // batch
  const int wi   = blockIdx.x & 63;   // window index
  const int n1   = wi >> 3, n2 = wi & 7;
  const f32x4 fzero = {0.f, 0.f, 0.f, 0.f};

  // ---------------- Phase 0: load x window, pre-LN, write A (bf16) ----------------
  {
    const int p8 = tid >> 3;   // pixel slot 0..63
    const int sub = tid & 7;   // 8 threads per pixel, 32 ch each
    float vals[32];
    float s = 0.f, s2 = 0.f;
    if (p8 < 49) {
      const int r = p8 / 7, c = p8 - r * 7;
      const int hh = r * 8 + n1, ww = c * 8 + n2;
      const float* xp = x + (size_t)bb * 256 * 3136 + hh * 56 + ww;
      #pragma unroll
      for (int j = 0; j < 32; ++j) {
        float v = xp[(size_t)(sub * 32 + j) * 3136];
        vals[j] = v; s += v; s2 += v * v;
      }
    } else {
      #pragma unroll
      for (int j = 0; j < 32; ++j) vals[j] = 0.f;
    }
    #pragma unroll
    for (int m = 1; m < 8; m <<= 1) { s += __shfl_xor(s, m, 64); s2 += __shfl_xor(s2, m, 64); }
    const float mean = s * (1.f / 256.f);
    const float rstd = rsqrtf(s2 * (1.f / 256.f) - mean * mean + 1e-5f);
    #pragma unroll
    for (int q = 0; q < 4; ++q) {
      bf16x8 pk;
      #pragma unroll
      for (int j = 0; j < 8; ++j) {
        const int ch = sub * 32 + q * 8 + j;
        float nv = 0.f;
        if (p8 < 49) nv = (vals[q * 8 + j] - mean) * rstd * pre_g[ch] + pre_b[ch];
        pk[j] = (bf16)nv;
      }
      *(bf16x8*)(Abase + p8 * 512 + swz(p8, (uint32_t)(sub * 64 + q * 16))) = pk;
    }
  }
  __syncthreads();

  // ---------------- Phase 1: qk GEMM (M=64,N=512,K=256) -> QK lds ----------------
  {
    const int cb = wv * 64;
    f32x4 acc[4][4];
    #pragma unroll
    for (int i = 0; i < 4; ++i)
      #pragma unroll
      for (int j = 0; j < 4; ++j) acc[i][j] = fzero;
    for (int ks = 0; ks < 8; ++ks) {
      const int kb = ks * 32 + g4 * 8;
      bf16x8 af[4];
      #pragma unroll
      for (int mt = 0; mt < 4; ++mt) {
        const int row = mt * 16 + l15;
        af[mt] = *(const bf16x8*)(Abase + row * 512 + swz(row, (uint32_t)(kb * 2)));
      }
      #pragma unroll
      for (int nt = 0; nt < 4; ++nt) {
        const int col = cb + nt * 16 + l15;
        const bf16x8 bfv = *(const bf16x8*)(wqkv + (size_t)col * 256 + kb);
        #pragma unroll
        for (int mt = 0; mt < 4; ++mt)
          acc[mt][nt] = __builtin_amdgcn_mfma_f32_16x16x32_bf16(af[mt], bfv, acc[mt][nt], 0, 0, 0);
      }
    }
    #pragma unroll
    for (int nt = 0; nt < 4; ++nt) {
      const int ch = cb + nt * 16 + l15;
      const float qb = qk_bias[ch];
      const int sel = ch >> 8, head = (ch >> 5) & 7, d = ch & 31;
      char* base = R2 + head * 7168;
      const uint32_t colb = (uint32_t)((sel * 32 + d) * 2);
      #pragma unroll
      for (int mt = 0; mt < 4; ++mt)
        #pragma unroll
        for (int r = 0; r < 4; ++r) {
          const int n = mt * 16 + g4 * 4 + r;
          if (n < 56) *(bf16*)(base + n * 128 + swz(n, colb)) = (bf16)(acc[mt][nt][r] + qb);
        }
    }
  }
  __syncthreads();

  // ---------------- Phase 2: scores + bias + softmax -> ATT (wave = head) ----------------
  {
    const int h = wv;
    const char* QK = R2 + h * 7168;
    char* at = ATT + h * 7168;
    f32x4 sa[4][4];
    #pragma unroll
    for (int i = 0; i < 4; ++i)
      #pragma unroll
      for (int j = 0; j < 4; ++j) sa[i][j] = fzero;
    const int kq = g4 * 8;
    bf16x8 qf[4];
    #pragma unroll
    for (int mt = 0; mt < 4; ++mt) {
      const int row = imin(mt * 16 + l15, 55);
      qf[mt] = *(const bf16x8*)(QK + row * 128 + swz(row, (uint32_t)(kq * 2)));
    }
    #pragma unroll
    for (int nt = 0; nt < 4; ++nt) {
      const int mrow = imin(nt * 16 + l15, 55);
      const bf16x8 kf = *(const bf16x8*)(QK + mrow * 128 + swz(mrow, (uint32_t)(64 + kq * 2)));
      #pragma unroll
      for (int mt = 0; mt < 4; ++mt)
        sa[mt][nt] = __builtin_amdgcn_mfma_f32_16x16x32_bf16(qf[mt], kf, sa[mt][nt], 0, 0, 0);
    }
    #pragma unroll
    for (int mt = 0; mt < 4; ++mt)
      #pragma unroll
      for (int r = 0; r < 4; ++r) {
        const int n = mt * 16 + g4 * 4 + r;
        const int rn = n / 7, cn = n - rn * 7;
        float v[4];
        #pragma unroll
        for (int nt = 0; nt < 4; ++nt) {
          const int m = nt * 16 + l15;
          float sv = sa[mt][nt][r] * 0.17677669529663687f;
          if (n < 49 && m < 49) {
            const int rm = m / 7, cm = m - rm * 7;
            sv += rpb[((size_t)wi * 169 + (size_t)((rn - rm + 6) * 13 + (cn - cm + 6))) * 8 + h];
          } else {
            sv = -1e30f;
          }
          v[nt] = sv;
        }
        float mx = fmaxf(fmaxf(v[0], v[1]), fmaxf(v[2], v[3]));
        #pragma unroll
        for (int mm = 1; mm < 16; mm <<= 1) mx = fmaxf(mx, __shfl_xor(mx, mm, 64));
        float sum = 0.f;
        #pragma unroll
        for (int nt = 0; nt < 4; ++nt) { v[nt] = expf(v[nt] - mx); sum += v[nt]; }
        #pragma unroll
        for (int mm = 1; mm < 16; mm <<= 1) sum += __shfl_xor(sum, mm, 64);
        const float inv = 1.f / sum;
        #pragma unroll
        for (int nt = 0; nt < 4; ++nt)
          if (n < 56) *(bf16*)(at + n * 128 + swz(n, (uint32_t)((nt * 16 + l15) * 2))) = (bf16)(v[nt] * inv);
      }
  }
  __syncthreads();

  // ---------------- Phase 3a: v_attn GEMM (wave = head, N=64) -> V lds (transposed) ----------------
  {
    const int h = wv;
    f32x4 acc[4][4];
    #pragma unroll
    for (int i = 0; i < 4; ++i)
      #pragma unroll
      for (int j = 0; j < 4; ++j) acc[i][j] = fzero;
    for (int ks = 0; ks < 8; ++ks) {
      const int kb = ks * 32 + g4 * 8;
      bf16x8 af[4];
      #pragma unroll
      for (int mt = 0; mt < 4; ++mt) {
        const int row = mt * 16 + l15;
        af[mt] = *(const bf16x8*)(Abase + row * 512 + swz(row, (uint32_t)(kb * 2)));
      }
      #pragma unroll
      for (int nt = 0; nt < 4; ++nt) {
        const int col = 512 + h * 64 + nt * 16 + l15;
        const bf16x8 bfv = *(const bf16x8*)(wqkv + (size_t)col * 256 + kb);
        #pragma unroll
        for (int mt = 0; mt < 4; ++mt)
          acc[mt][nt] = __builtin_amdgcn_mfma_f32_16x16x32_bf16(af[mt], bfv, acc[mt][nt], 0, 0, 0);
      }
    }
    char* V = R2 + h * 8192;
    #pragma unroll
    for (int nt = 0; nt < 4; ++nt) {
      const int vd = nt * 16 + l15;
      const float vb = v_bias[h * 64 + vd];
      #pragma unroll
      for (int mt = 0; mt < 4; ++mt)
        #pragma unroll
        for (int r = 0; r < 4; ++r) {
          const int m = mt * 16 + g4 * 4 + r;
          *(bf16*)(V + vd * 128 + swz(vd, (uint32_t)(m * 2))) = (bf16)(acc[mt][nt][r] + vb);
        }
    }
  }
  __syncthreads();

  // ---------------- Phase 3b: PV (M=64,N=64,K=64) ----------------
  f32x4 oacc[4][4];
  {
    const int h = wv;
    const char* at = ATT + h * 7168;
    const char* V = R2 + h * 8192;
    #pragma unroll
    for (int i = 0; i < 4; ++i)
      #pragma unroll
      for (int j = 0; j < 4; ++j) oacc[i][j] = fzero;
    #pragma unroll
    for (int ks = 0; ks < 2; ++ks) {
      const int kb = ks * 32 + g4 * 8;
      bf16x8 af[4];
      #pragma unroll
      for (int mt = 0; mt < 4; ++mt) {
        const int row = imin(mt * 16 + l15, 55);
        af[mt] = *(const bf16x8*)(at + row * 128 + swz(row, (uint32_t)(kb * 2)));
      }
      #pragma unroll
      for (int nt = 0; nt < 4; ++nt) {
        const int vd = nt * 16 + l15;
        const bf16x8 bfv = *(const bf16x8*)(V + vd * 128 + swz(vd, (uint32_t)(kb * 2)));
        #pragma unroll
        for (int mt = 0; mt < 4; ++mt)
          oacc[mt][nt] = __builtin_amdgcn_mfma_f32_16x16x32_bf16(af[mt], bfv, oacc[mt][nt], 0, 0, 0);
      }
    }
  }
  __syncthreads();   // ATT/V regions about to be overwritten by XM

  // ---------------- Phase 4a-1: write o -> XM[:, h*64+vd] ----------------
  {
    const int h = wv;
    #pragma unroll
    for (int nt = 0; nt < 4; ++nt) {
      const int ch = h * 64 + nt * 16 + l15;
      #pragma unroll
      for (int mt = 0; mt < 4; ++mt)
        #pragma unroll
        for (int r = 0; r < 4; ++r) {
          const int n = mt * 16 + g4 * 4 + r;
          if (n < 56) *(bf16*)(XMb + n * 2048 + swz(n, (uint32_t)(ch * 2))) = (bf16)oacc[mt][nt][r];
        }
    }
  }
  // ---------------- Phase 4b: v_idle GEMM -> gelu -> XM[:, 512:1024] ----------------
  {
    f32x4 acc[4][4];
    #pragma unroll
    for (int i = 0; i < 4; ++i)
      #pragma unroll
      for (int j = 0; j < 4; ++j) acc[i][j] = fzero;
    for (int ks = 0; ks < 8; ++ks) {
      const int kb = ks * 32 + g4 * 8;
      bf16x8 af[4];
      #pragma unroll
      for (int mt = 0; mt < 4; ++mt) {
        const int row = mt * 16 + l15;
        af[mt] = *(const bf16x8*)(Abase + row * 512 + swz(row, (uint32_t)(kb * 2)));
      }
      #pragma unroll
      for (int nt = 0; nt < 4; ++nt) {
        const int fcol = 1024 + wv * 64 + nt * 16 + l15;
        const bf16x8 bfv = *(const bf16x8*)(wqkv + (size_t)fcol * 256 + kb);
        #pragma unroll
        for (int mt = 0; mt < 4; ++mt)
          acc[mt][nt] = __builtin_amdgcn_mfma_f32_16x16x32_bf16(af[mt], bfv, acc[mt][nt], 0, 0, 0);
      }
    }
    #pragma unroll
    for (int nt = 0; nt < 4; ++nt) {
      const int fcol = 1024 + wv * 64 + nt * 16 + l15;
      const int vc = fcol - 512;            // v channel in [512,1024) == xm channel
      const float vb = v_bias[vc];
      #pragma unroll
      for (int mt = 0; mt < 4; ++mt)
        #pragma unroll
        for (int r = 0; r < 4; ++r) {
          const int n = mt * 16 + g4 * 4 + r;
          if (n < 56) *(bf16*)(XMb + n * 2048 + swz(n, (uint32_t)(vc * 2))) = (bf16)gelu_f(acc[mt][nt][r] + vb);
        }
    }
  }
  __syncthreads();

  // ---------------- Phase 4a-2: post-LN + gelu on XM[:, :512] ----------------
  {
    const int p8 = tid >> 3, sub = tid & 7;
    float s = 0.f, s2 = 0.f;
    if (p8 < 56) {
      #pragma unroll
      for (int q = 0; q < 8; ++q) {
        const bf16x8 v8 = *(const bf16x8*)(XMb + p8 * 2048 + swz(p8, (uint32_t)(sub * 128 + q * 16)));
        #pragma unroll
        for (int e = 0; e < 8; ++e) { const float v = (float)v8[e]; s += v; s2 += v * v; }
      }
    }
    #pragma unroll
    for (int m = 1; m < 8; m <<= 1) { s += __shfl_xor(s, m, 64); s2 += __shfl_xor(s2, m, 64); }
    const float mean = s * (1.f / 512.f);
    const float rstd = rsqrtf(s2 * (1.f / 512.f) - mean * mean + 1e-5f);
    if (p8 < 56) {
      #pragma unroll
      for (int q = 0; q < 8; ++q) {
        bf16x8* p = (bf16x8*)(XMb + p8 * 2048 + swz(p8, (uint32_t)(sub * 128 + q * 16)));
        bf16x8 v8 = *p;
        #pragma unroll
        for (int e = 0; e < 8; ++e) {
          const int ch = sub * 64 + q * 8 + e;
          const float v = ((float)v8[e] - mean) * rstd * post_g[ch] + post_b[ch];
          v8[e] = (bf16)gelu_f(v);
        }
        *p = v8;
      }
    }
  }
  __syncthreads();

  // ---------------- Phase 5: proj GEMM (M=64,N=256,K=1024) + bias + residual + roll ----------------
  {
    const int cb = wv * 32;
    f32x4 acc[4][2];
    #pragma unroll
    for (int i = 0; i < 4; ++i)
      #pragma unroll
      for (int j = 0; j < 2; ++j) acc[i][j] = fzero;
    for (int ks = 0; ks < 32; ++ks) {
      const int kb = ks * 32 + g4 * 8;
      bf16x8 af[4];
      #pragma unroll
      for (int mt = 0; mt < 4; ++mt) {
        const int row = imin(mt * 16 + l15, 55);
        af[mt] = *(const bf16x8*)(XMb + row * 2048 + swz(row, (uint32_t)(kb * 2)));
      }
      #pragma unroll
      for (int nt = 0; nt < 2; ++nt) {
        const int col = cb + nt * 16 + l15;
        const bf16x8 bfv = *(const bf16x8*)(wproj + (size_t)col * 1024 + kb);
        #pragma unroll
        for (int mt = 0; mt < 4; ++mt)
          acc[mt][nt] = __builtin_amdgcn_mfma_f32_16x16x32_bf16(af[mt], bfv, acc[mt][nt], 0, 0, 0);
      }
    }
    #pragma unroll
    for (int nt = 0; nt < 2; ++nt) {
      const int oc = cb + nt * 16 + l15;
      const float pb = proj_bias[oc];
      #pragma unroll
      for (int mt = 0; mt < 4; ++mt)
        #pragma unroll
        for (int r = 0; r < 4; ++r) {
          const int n = mt * 16 + g4 * 4 + r;
          if (n < 49) {
            const int rr = n / 7, cc = n - rr * 7;
            const int hh = rr * 8 + n1, ww = cc * 8 + n2;
            const size_t ci = ((size_t)bb * 256 + oc) * 3136;
            const float val = acc[mt][nt][r] + pb + x[ci + hh * 56 + ww];
            int h2 = hh + 2; if (h2 >= 56) h2 -= 56;
            int w2 = ww + 2; if (w2 >= 56) w2 -= 56;
            out[ci + h2 * 56 + w2] = val;
          }
        }
    }
  }
}

extern "C" void kernel_launch(void* const* d_in, const int* in_sizes, int n_in,
                              void* d_out, int out_size, void* d_ws, size_t ws_size,
                              hipStream_t stream) {
  const float* x      = (const float*)d_in[0];
  const float* pre_g  = (const float*)d_in[1];
  const float* pre_b  = (const float*)d_in[2];
  const float* post_g = (const float*)d_in[3];
  const float* post_b = (const float*)d_in[4];
  const float* qk_w   = (const float*)d_in[5];
  const float* qk_b   = (const float*)d_in[6];
  const float* v_w    = (const float*)d_in[7];
  const float* v_b    = (const float*)d_in[8];
  const float* proj_w = (const float*)d_in[9];
  const float* proj_b = (const float*)d_in[10];
  const float* rpb    = (const float*)d_in[11];

  bf16* wqkv  = (bf16*)d_ws;            // 393216 bf16
  bf16* wproj = wqkv + 393216;          // 262144 bf16

  conv_w_kernel<<<2560, 256, 0, stream>>>(qk_w, v_w, proj_w, wqkv, wproj);

  const int smem_bytes = 155648;
  (void)hipFuncSetAttribute((const void*)irmb_main,
                            hipFuncAttributeMaxDynamicSharedMemorySize, smem_bytes);
  irmb_main<<<2048, 512, smem_bytes, stream>>>(
      x, pre_g, pre_b, post_g, post_b, qk_b, v_b, proj_b, rpb,
      wqkv, wproj, (float*)d_out);
}

// Round 2
// 1041.114 us; speedup vs baseline: 1.1703x; 1.1703x over previous
//
#include <hip/hip_runtime.h>
#include <math.h>

using bf16 = __bf16;
using bf16x8 = __attribute__((ext_vector_type(8))) __bf16;
using f32x4 = __attribute__((ext_vector_type(4))) float;

static __device__ __forceinline__ int imin(int a, int b) { return a < b ? a : b; }
// XOR swizzle: 16B-chunk rotate within a row, bits 4-6, keyed by row&7.
static __device__ __forceinline__ uint32_t swz(int row, uint32_t colb) {
  return colb ^ (uint32_t)((row & 7) << 4);
}
static __device__ __forceinline__ float gelu_f(float v) {
  return 0.5f * v * (1.0f + erff(v * 0.7071067811865475f));
}

// ---- weight conversion: fp32 -> bf16 into workspace ----
__global__ void conv_w_kernel(const float* __restrict__ qk_w,
                              const float* __restrict__ v_w,
                              const float* __restrict__ proj_w,
                              bf16* __restrict__ wqkv,
                              bf16* __restrict__ wproj) {
  int i = blockIdx.x * 256 + threadIdx.x;
  if (i < 131072)       wqkv[i] = (bf16)qk_w[i];
  else if (i < 393216)  wqkv[i] = (bf16)v_w[i - 131072];
  else if (i < 655360)  wproj[i - 393216] = (bf16)proj_w[i - 393216];
}

// LDS layout (bytes), total 155648:
//   A   @ 0      : ln(x) bf16 [64][256], row stride 512B, swizzled (rows 49..63 zero)
//   ATT @ 32768  : attn bf16 [8 heads][56][64], row stride 128B, swizzled
//   R2  @ 90112  : phase1-2: QK bf16 [8][56][64]; phase3+: V [8][64][64]
//   XM  @ 32768  : [56][1024] bf16, stride 2048B (overlays ATT+R2 after PV)
__global__ void __launch_bounds__(512, 2)
irmb_main(const float* __restrict__ x,
          const float* __restrict__ pre_g,  const float* __restrict__ pre_b,
          const float* __restrict__ post_g, const float* __restrict__ post_b,
          const float* __restrict__ qk_bias, const float* __restrict__ v_bias,
          const float* __restrict__ proj_bias, const float* __restrict__ rpb,
          const bf16* __restrict__ wqkv, const bf16* __restrict__ wproj,
          float* __restrict__ out)
{
  extern __shared__ char smem[];
  char* Abase = smem;
  char* ATT   = smem + 32768;
  char* R2    = smem + 90112;
  char* XMb   = smem + 32768;

  const int tid  = threadIdx.x;
  const int lane = tid & 63;
  const int wv   = tid >> 6;      // wave id 0..7
  const int l15  = lane & 15;
  const int g4   = lane >> 4;     // 0..3
  // XCD-aware bijective remap (T1): grid=2048, 8 XCDs, chunk=256.
  // All 64 windows of a batch land on ONE XCD -> x/out cache lines are
  // fetched/written by a single L2 instead of all eight.
  const int wid  = (blockIdx.x & 7) * 256 + (blockIdx.x >> 3);
  const int bb   = wid >> 6;          // batch
  const int wi   = wid & 63;          // window index
  const int n1   = wi >> 3, n2 = wi & 7;
  const f32x4 fzero = {0.f, 0.f, 0.f, 0.f};

  // ---------------- Phase 0: load x window, pre-LN, write A (bf16) ----------------
  {
    const int p8 = tid >> 3;   // pixel slot 0..63
    const int sub = tid & 7;   // 8 threads per pixel, 32 ch each
    float vals[32];
    float s = 0.f, s2 = 0.f;
    if (p8 < 49) {
      const int r = p8 / 7, c = p8 - r * 7;
      const int hh = r * 8 + n1, ww = c * 8 + n2;
      const float* xp = x + (size_t)bb * 256 * 3136 + hh * 56 + ww;
      #pragma unroll
      for (int j = 0; j < 32; ++j) {
        float v = xp[(size_t)(sub * 32 + j) * 3136];
        vals[j] = v; s += v; s2 += v * v;
      }
    } else {
      #pragma unroll
      for (int j = 0; j < 32; ++j) vals[j] = 0.f;
    }
    #pragma unroll
    for (int m = 1; m < 8; m <<= 1) { s += __shfl_xor(s, m, 64); s2 += __shfl_xor(s2, m, 64); }
    const float mean = s * (1.f / 256.f);
    const float rstd = rsqrtf(s2 * (1.f / 256.f) - mean * mean + 1e-5f);
    #pragma unroll
    for (int q = 0; q < 4; ++q) {
      bf16x8 pk;
      #pragma unroll
      for (int j = 0; j < 8; ++j) {
        const int ch = sub * 32 + q * 8 + j;
        float nv = 0.f;
        if (p8 < 49) nv = (vals[q * 8 + j] - mean) * rstd * pre_g[ch] + pre_b[ch];
        pk[j] = (bf16)nv;
      }
      *(bf16x8*)(Abase + p8 * 512 + swz(p8, (uint32_t)(sub * 64 + q * 16))) = pk;
    }
  }
  __syncthreads();

  // ---------------- Phase 1: qk GEMM (M=64,N=512,K=256) -> QK lds ----------------
  {
    const int cb = wv * 64;
    f32x4 acc[4][4];
    #pragma unroll
    for (int i = 0; i < 4; ++i)
      #pragma unroll
      for (int j = 0; j < 4; ++j) acc[i][j] = fzero;
    for (int ks = 0; ks < 8; ++ks) {
      const int kb = ks * 32 + g4 * 8;
      bf16x8 af[4];
      #pragma unroll
      for (int mt = 0; mt < 4; ++mt) {
        const int row = mt * 16 + l15;
        af[mt] = *(const bf16x8*)(Abase + row * 512 + swz(row, (uint32_t)(kb * 2)));
      }
      #pragma unroll
      for (int nt = 0; nt < 4; ++nt) {
        const int col = cb + nt * 16 + l15;
        const bf16x8 bfv = *(const bf16x8*)(wqkv + (size_t)col * 256 + kb);
        #pragma unroll
        for (int mt = 0; mt < 4; ++mt)
          acc[mt][nt] = __builtin_amdgcn_mfma_f32_16x16x32_bf16(af[mt], bfv, acc[mt][nt], 0, 0, 0);
      }
    }
    #pragma unroll
    for (int nt = 0; nt < 4; ++nt) {
      const int ch = cb + nt * 16 + l15;
      const float qb = qk_bias[ch];
      const int sel = ch >> 8, head = (ch >> 5) & 7, d = ch & 31;
      char* base = R2 + head * 7168;
      const uint32_t colb = (uint32_t)((sel * 32 + d) * 2);
      #pragma unroll
      for (int mt = 0; mt < 4; ++mt)
        #pragma unroll
        for (int r = 0; r < 4; ++r) {
          const int n = mt * 16 + g4 * 4 + r;
          if (n < 56) *(bf16*)(base + n * 128 + swz(n, colb)) = (bf16)(acc[mt][nt][r] + qb);
        }
    }
  }
  __syncthreads();

  // ---------------- Phase 2: scores + bias + softmax -> ATT (wave = head) ----------------
  {
    const int h = wv;
    const char* QK = R2 + h * 7168;
    char* at = ATT + h * 7168;
    f32x4 sa[4][4];
    #pragma unroll
    for (int i = 0; i < 4; ++i)
      #pragma unroll
      for (int j = 0; j < 4; ++j) sa[i][j] = fzero;
    const int kq = g4 * 8;
    bf16x8 qf[4];
    #pragma unroll
    for (int mt = 0; mt < 4; ++mt) {
      const int row = imin(mt * 16 + l15, 55);
      qf[mt] = *(const bf16x8*)(QK + row * 128 + swz(row, (uint32_t)(kq * 2)));
    }
    #pragma unroll
    for (int nt = 0; nt < 4; ++nt) {
      const int mrow = imin(nt * 16 + l15, 55);
      const bf16x8 kf = *(const bf16x8*)(QK + mrow * 128 + swz(mrow, (uint32_t)(64 + kq * 2)));
      #pragma unroll
      for (int mt = 0; mt < 4; ++mt)
        sa[mt][nt] = __builtin_amdgcn_mfma_f32_16x16x32_bf16(qf[mt], kf, sa[mt][nt], 0, 0, 0);
    }
    #pragma unroll
    for (int mt = 0; mt < 4; ++mt)
      #pragma unroll
      for (int r = 0; r < 4; ++r) {
        const int n = mt * 16 + g4 * 4 + r;
        const int rn = n / 7, cn = n - rn * 7;
        float v[4];
        #pragma unroll
        for (int nt = 0; nt < 4; ++nt) {
          const int m = nt * 16 + l15;
          float sv = sa[mt][nt][r] * 0.17677669529663687f;
          if (n < 49 && m < 49) {
            const int rm = m / 7, cm = m - rm * 7;
            sv += rpb[((size_t)wi * 169 + (size_t)((rn - rm + 6) * 13 + (cn - cm + 6))) * 8 + h];
          } else {
            sv = -1e30f;
          }
          v[nt] = sv;
        }
        float mx = fmaxf(fmaxf(v[0], v[1]), fmaxf(v[2], v[3]));
        #pragma unroll
        for (int mm = 1; mm < 16; mm <<= 1) mx = fmaxf(mx, __shfl_xor(mx, mm, 64));
        float sum = 0.f;
        #pragma unroll
        for (int nt = 0; nt < 4; ++nt) { v[nt] = expf(v[nt] - mx); sum += v[nt]; }
        #pragma unroll
        for (int mm = 1; mm < 16; mm <<= 1) sum += __shfl_xor(sum, mm, 64);
        const float inv = 1.f / sum;
        #pragma unroll
        for (int nt = 0; nt < 4; ++nt)
          if (n < 56) *(bf16*)(at + n * 128 + swz(n, (uint32_t)((nt * 16 + l15) * 2))) = (bf16)(v[nt] * inv);
      }
  }
  __syncthreads();

  // ---------------- Phase 3a: v_attn GEMM (wave = head, N=64) -> V lds (transposed) ----------------
  {
    const int h = wv;
    f32x4 acc[4][4];
    #pragma unroll
    for (int i = 0; i < 4; ++i)
      #pragma unroll
      for (int j = 0; j < 4; ++j) acc[i][j] = fzero;
    for (int ks = 0; ks < 8; ++ks) {
      const int kb = ks * 32 + g4 * 8;
      bf16x8 af[4];
      #pragma unroll
      for (int mt = 0; mt < 4; ++mt) {
        const int row = mt * 16 + l15;
        af[mt] = *(const bf16x8*)(Abase + row * 512 + swz(row, (uint32_t)(kb * 2)));
      }
      #pragma unroll
      for (int nt = 0; nt < 4; ++nt) {
        const int col = 512 + h * 64 + nt * 16 + l15;
        const bf16x8 bfv = *(const bf16x8*)(wqkv + (size_t)col * 256 + kb);
        #pragma unroll
        for (int mt = 0; mt < 4; ++mt)
          acc[mt][nt] = __builtin_amdgcn_mfma_f32_16x16x32_bf16(af[mt], bfv, acc[mt][nt], 0, 0, 0);
      }
    }
    char* V = R2 + h * 8192;
    #pragma unroll
    for (int nt = 0; nt < 4; ++nt) {
      const int vd = nt * 16 + l15;
      const float vb = v_bias[h * 64 + vd];
      #pragma unroll
      for (int mt = 0; mt < 4; ++mt)
        #pragma unroll
        for (int r = 0; r < 4; ++r) {
          const int m = mt * 16 + g4 * 4 + r;
          *(bf16*)(V + vd * 128 + swz(vd, (uint32_t)(m * 2))) = (bf16)(acc[mt][nt][r] + vb);
        }
    }
  }
  __syncthreads();

  // ---------------- Phase 3b: PV (M=64,N=64,K=64) ----------------
  f32x4 oacc[4][4];
  {
    const int h = wv;
    const char* at = ATT + h * 7168;
    const char* V = R2 + h * 8192;
    #pragma unroll
    for (int i = 0; i < 4; ++i)
      #pragma unroll
      for (int j = 0; j < 4; ++j) oacc[i][j] = fzero;
    #pragma unroll
    for (int ks = 0; ks < 2; ++ks) {
      const int kb = ks * 32 + g4 * 8;
      bf16x8 af[4];
      #pragma unroll
      for (int mt = 0; mt < 4; ++mt) {
        const int row = imin(mt * 16 + l15, 55);
        af[mt] = *(const bf16x8*)(at + row * 128 + swz(row, (uint32_t)(kb * 2)));
      }
      #pragma unroll
      for (int nt = 0; nt < 4; ++nt) {
        const int vd = nt * 16 + l15;
        const bf16x8 bfv = *(const bf16x8*)(V + vd * 128 + swz(vd, (uint32_t)(kb * 2)));
        #pragma unroll
        for (int mt = 0; mt < 4; ++mt)
          oacc[mt][nt] = __builtin_amdgcn_mfma_f32_16x16x32_bf16(af[mt], bfv, oacc[mt][nt], 0, 0, 0);
      }
    }
  }
  __syncthreads();   // ATT/V regions about to be overwritten by XM

  // ---------------- Phase 4a-1: write o -> XM[:, h*64+vd] ----------------
  {
    const int h = wv;
    #pragma unroll
    for (int nt = 0; nt < 4; ++nt) {
      const int ch = h * 64 + nt * 16 + l15;
      #pragma unroll
      for (int mt = 0; mt < 4; ++mt)
        #pragma unroll
        for (int r = 0; r < 4; ++r) {
          const int n = mt * 16 + g4 * 4 + r;
          if (n < 56) *(bf16*)(XMb + n * 2048 + swz(n, (uint32_t)(ch * 2))) = (bf16)oacc[mt][nt][r];
        }
    }
  }
  // ---------------- Phase 4b: v_idle GEMM -> gelu -> XM[:, 512:1024] ----------------
  {
    f32x4 acc[4][4];
    #pragma unroll
    for (int i = 0; i < 4; ++i)
      #pragma unroll
      for (int j = 0; j < 4; ++j) acc[i][j] = fzero;
    for (int ks = 0; ks < 8; ++ks) {
      const int kb = ks * 32 + g4 * 8;
      bf16x8 af[4];
      #pragma unroll
      for (int mt = 0; mt < 4; ++mt) {
        const int row = mt * 16 + l15;
        af[mt] = *(const bf16x8*)(Abase + row * 512 + swz(row, (uint32_t)(kb * 2)));
      }
      #pragma unroll
      for (int nt = 0; nt < 4; ++nt) {
        const int fcol = 1024 + wv * 64 + nt * 16 + l15;
        const bf16x8 bfv = *(const bf16x8*)(wqkv + (size_t)fcol * 256 + kb);
        #pragma unroll
        for (int mt = 0; mt < 4; ++mt)
          acc[mt][nt] = __builtin_amdgcn_mfma_f32_16x16x32_bf16(af[mt], bfv, acc[mt][nt], 0, 0, 0);
      }
    }
    #pragma unroll
    for (int nt = 0; nt < 4; ++nt) {
      const int fcol = 1024 + wv * 64 + nt * 16 + l15;
      const int vc = fcol - 512;            // v channel in [512,1024) == xm channel
      const float vb = v_bias[vc];
      #pragma unroll
      for (int mt = 0; mt < 4; ++mt)
        #pragma unroll
        for (int r = 0; r < 4; ++r) {
          const int n = mt * 16 + g4 * 4 + r;
          if (n < 56) *(bf16*)(XMb + n * 2048 + swz(n, (uint32_t)(vc * 2))) = (bf16)gelu_f(acc[mt][nt][r] + vb);
        }
    }
  }
  __syncthreads();

  // ---------------- Phase 4a-2: post-LN + gelu on XM[:, :512] ----------------
  {
    const int p8 = tid >> 3, sub = tid & 7;
    float s = 0.f, s2 = 0.f;
    if (p8 < 56) {
      #pragma unroll
      for (int q = 0; q < 8; ++q) {
        const bf16x8 v8 = *(const bf16x8*)(XMb + p8 * 2048 + swz(p8, (uint32_t)(sub * 128 + q * 16)));
        #pragma unroll
        for (int e = 0; e < 8; ++e) { const float v = (float)v8[e]; s += v; s2 += v * v; }
      }
    }
    #pragma unroll
    for (int m = 1; m < 8; m <<= 1) { s += __shfl_xor(s, m, 64); s2 += __shfl_xor(s2, m, 64); }
    const float mean = s * (1.f / 512.f);
    const float rstd = rsqrtf(s2 * (1.f / 512.f) - mean * mean + 1e-5f);
    if (p8 < 56) {
      #pragma unroll
      for (int q = 0; q < 8; ++q) {
        bf16x8* p = (bf16x8*)(XMb + p8 * 2048 + swz(p8, (uint32_t)(sub * 128 + q * 16)));
        bf16x8 v8 = *p;
        #pragma unroll
        for (int e = 0; e < 8; ++e) {
          const int ch = sub * 64 + q * 8 + e;
          const float v = ((float)v8[e] - mean) * rstd * post_g[ch] + post_b[ch];
          v8[e] = (bf16)gelu_f(v);
        }
        *p = v8;
      }
    }
  }
  __syncthreads();

  // ---------------- Phase 5: proj GEMM (M=64,N=256,K=1024) + bias + residual + roll ----------------
  {
    const int cb = wv * 32;
    f32x4 acc[4][2];
    #pragma unroll
    for (int i = 0; i < 4; ++i)
      #pragma unroll
      for (int j = 0; j < 2; ++j) acc[i][j] = fzero;
    for (int ks = 0; ks < 32; ++ks) {
      const int kb = ks * 32 + g4 * 8;
      bf16x8 af[4];
      #pragma unroll
      for (int mt = 0; mt < 4; ++mt) {
        const int row = imin(mt * 16 + l15, 55);
        af[mt] = *(const bf16x8*)(XMb + row * 2048 + swz(row, (uint32_t)(kb * 2)));
      }
      #pragma unroll
      for (int nt = 0; nt < 2; ++nt) {
        const int col = cb + nt * 16 + l15;
        const bf16x8 bfv = *(const bf16x8*)(wproj + (size_t)col * 1024 + kb);
        #pragma unroll
        for (int mt = 0; mt < 4; ++mt)
          acc[mt][nt] = __builtin_amdgcn_mfma_f32_16x16x32_bf16(af[mt], bfv, acc[mt][nt], 0, 0, 0);
      }
    }
    #pragma unroll
    for (int nt = 0; nt < 2; ++nt) {
      const int oc = cb + nt * 16 + l15;
      const float pb = proj_bias[oc];
      #pragma unroll
      for (int mt = 0; mt < 4; ++mt)
        #pragma unroll
        for (int r = 0; r < 4; ++r) {
          const int n = mt * 16 + g4 * 4 + r;
          if (n < 49) {
            const int rr = n / 7, cc = n - rr * 7;
            const int hh = rr * 8 + n1, ww = cc * 8 + n2;
            const size_t ci = ((size_t)bb * 256 + oc) * 3136;
            const float val = acc[mt][nt][r] + pb + x[ci + hh * 56 + ww];
            int h2 = hh + 2; if (h2 >= 56) h2 -= 56;
            int w2 = ww + 2; if (w2 >= 56) w2 -= 56;
            out[ci + h2 * 56 + w2] = val;
          }
        }
    }
  }
}

extern "C" void kernel_launch(void* const* d_in, const int* in_sizes, int n_in,
                              void* d_out, int out_size, void* d_ws, size_t ws_size,
                              hipStream_t stream) {
  const float* x      = (const float*)d_in[0];
  const float* pre_g  = (const float*)d_in[1];
  const float* pre_b  = (const float*)d_in[2];
  const float* post_g = (const float*)d_in[3];
  const float* post_b = (const float*)d_in[4];
  const float* qk_w   = (const float*)d_in[5];
  const float* qk_b   = (const float*)d_in[6];
  const float* v_w    = (const float*)d_in[7];
  const float* v_b    = (const float*)d_in[8];
  const float* proj_w = (const float*)d_in[9];
  const float* proj_b = (const float*)d_in[10];
  const float* rpb    = (const float*)d_in[11];

  bf16* wqkv  = (bf16*)d_ws;            // 393216 bf16
  bf16* wproj = wqkv + 393216;          // 262144 bf16

  conv_w_kernel<<<2560, 256, 0, stream>>>(qk_w, v_w, proj_w, wqkv, wproj);

  const int smem_bytes = 155648;
  (void)hipFuncSetAttribute((const void*)irmb_main,
                            hipFuncAttributeMaxDynamicSharedMemorySize, smem_bytes);
  irmb_main<<<2048, 512, smem_bytes, stream>>>(
      x, pre_g, pre_b, post_g, post_b, qk_b, v_b, proj_b, rpb,
      wqkv, wproj, (float*)d_out);
}